// Round 1
// baseline (10736.528 us; speedup 1.0000x reference)
//
#include <hip/hip_runtime.h>
#include <math.h>

#define NB 64
#define NT 512
#define ND 512
#define NH 256
#define NG 1024   // 4*H
#define NK 32
#define NBT (NB*NT)

__device__ __forceinline__ float sigf(float x) { return 1.f / (1.f + expf(-x)); }

// ---------------- Whh layout transform: wsW[dir][v][4u+k] = Whh_dir[k*256+u][v]
__global__ void k_wprep(const float* __restrict__ Wf, const float* __restrict__ Wb,
                        float* __restrict__ wsW) {
    int idx = blockIdx.x * 256 + threadIdx.x;   // 0 .. 524287
    int dir = idx >> 18;
    int rem = idx & 262143;
    int v   = rem >> 10;
    int col = rem & 1023;
    int u = col >> 2, k = col & 3;
    const float* W = dir ? Wb : Wf;
    wsW[idx] = W[(k * NH + u) * NH + v];
}

// ---------------- xp = x @ Wih^T + b   (fp32 tiled GEMM, 64x64 tile, 4x4/thread)
__global__ __launch_bounds__(256)
void k_gemm_xp(const float* __restrict__ A, const float* __restrict__ W,
               const float* __restrict__ bias, float* __restrict__ C) {
    __shared__ float As[16][68];
    __shared__ float Ws[16][68];
    int tid = threadIdx.x;
    int tx = tid & 15, ty = tid >> 4;
    int row0 = blockIdx.y << 6, col0 = blockIdx.x << 6;
    int lr = tid >> 2;
    int lk = (tid & 3) << 2;
    const float* Ap = A + (size_t)(row0 + lr) * ND + lk;
    const float* Wp = W + (size_t)(col0 + lr) * ND + lk;
    float acc[4][4] = {};
    for (int kt = 0; kt < ND; kt += 16) {
        float4 av = *(const float4*)(Ap + kt);
        float4 wv = *(const float4*)(Wp + kt);
        As[lk + 0][lr] = av.x; As[lk + 1][lr] = av.y; As[lk + 2][lr] = av.z; As[lk + 3][lr] = av.w;
        Ws[lk + 0][lr] = wv.x; Ws[lk + 1][lr] = wv.y; Ws[lk + 2][lr] = wv.z; Ws[lk + 3][lr] = wv.w;
        __syncthreads();
        #pragma unroll
        for (int kk = 0; kk < 16; ++kk) {
            float4 a = *(const float4*)(&As[kk][ty << 2]);
            float4 w = *(const float4*)(&Ws[kk][tx << 2]);
            float a4[4] = {a.x, a.y, a.z, a.w};
            float w4[4] = {w.x, w.y, w.z, w.w};
            #pragma unroll
            for (int i = 0; i < 4; ++i)
                #pragma unroll
                for (int j = 0; j < 4; ++j)
                    acc[i][j] += a4[i] * w4[j];
        }
        __syncthreads();
    }
    float4 b4 = *(const float4*)(bias + col0 + (tx << 2));
    float bb[4] = {b4.x, b4.y, b4.z, b4.w};
    #pragma unroll
    for (int i = 0; i < 4; ++i) {
        float4 o;
        o.x = acc[i][0] + bb[0];
        o.y = acc[i][1] + bb[1];
        o.z = acc[i][2] + bb[2];
        o.w = acc[i][3] + bb[3];
        *(float4*)(C + (size_t)(row0 + (ty << 2) + i) * NG + col0 + (tx << 2)) = o;
    }
}

// ---------------- fused LSTM recurrence + partial classifier logits
// mode: 2 = concurrent (grid 64: blocks 0..31 fwd, 32..63 bwd); 0/1 = serial, that dir only (grid 32)
__global__ __launch_bounds__(256)
void k_lstm(const float* __restrict__ xpF, const float* __restrict__ xpB,
            const float* __restrict__ wsW,
            const float* __restrict__ Wclf, const float* __restrict__ bclf,
            const int* __restrict__ lengths,
            float* __restrict__ outF, float* __restrict__ outB,
            int mode) {
    int bi, dir;
    if (mode == 2) { dir = blockIdx.x >> 5; bi = blockIdx.x & 31; }
    else           { dir = mode;            bi = blockIdx.x; }
    const float* xp = dir ? xpB : xpF;
    float* out = dir ? outB : outF;
    const float* wdir = wsW + (size_t)dir * NH * NG;
    int b0 = bi * 2;
    int u = threadIdx.x;

    __shared__ float hbuf[2][NH];
    __shared__ float wcs[NK][257];   // pad 257: 2-way (free) LDS conflicts
    __shared__ float red[2][NK][9];  // pad 9: conflict-free

    #pragma unroll 4
    for (int kk = 0; kk < NK; ++kk)
        wcs[kk][u] = Wclf[kk * (2 * NH) + dir * NH + u];
    hbuf[0][u] = 0.f; hbuf[1][u] = 0.f;
    float c0 = 0.f, c1 = 0.f;
    int len0 = lengths[b0], len1 = lengths[b0 + 1];
    __syncthreads();

    int kkq = u & 31, seg = u >> 5;
    const float* wp = wdir + (u << 2);

    for (int tt = 0; tt < NT; ++tt) {
        int t = dir ? (NT - 1 - tt) : tt;
        bool a0 = t < len0, a1 = t < len1;
        if (a0 | a1) {
            const float* xr0 = xp + ((size_t)b0 * NT + t) * NG + u;
            const float* xr1 = xp + ((size_t)(b0 + 1) * NT + t) * NG + u;
            float x0[4], x1[4];
            #pragma unroll
            for (int k = 0; k < 4; ++k) { x0[k] = xr0[k * NH]; x1[k] = xr1[k * NH]; }
            float acc0[4] = {0.f, 0.f, 0.f, 0.f}, acc1[4] = {0.f, 0.f, 0.f, 0.f};
            #pragma unroll 2
            for (int v4 = 0; v4 < NH; v4 += 4) {
                float4 h0 = *(const float4*)(&hbuf[0][v4]);
                float4 h1 = *(const float4*)(&hbuf[1][v4]);
                float h0a[4] = {h0.x, h0.y, h0.z, h0.w};
                float h1a[4] = {h1.x, h1.y, h1.z, h1.w};
                #pragma unroll
                for (int q = 0; q < 4; ++q) {
                    float4 w = *(const float4*)(wp + (size_t)(v4 + q) * NG);
                    acc0[0] += h0a[q] * w.x; acc0[1] += h0a[q] * w.y;
                    acc0[2] += h0a[q] * w.z; acc0[3] += h0a[q] * w.w;
                    acc1[0] += h1a[q] * w.x; acc1[1] += h1a[q] * w.y;
                    acc1[2] += h1a[q] * w.z; acc1[3] += h1a[q] * w.w;
                }
            }
            __syncthreads();   // all hbuf reads done before overwrite
            if (a0) {
                float gi = sigf(acc0[0] + x0[0]);
                float gf = sigf(acc0[1] + x0[1]);
                float gg = tanhf(acc0[2] + x0[2]);
                float go = sigf(acc0[3] + x0[3]);
                c0 = gf * c0 + gi * gg;
                hbuf[0][u] = go * tanhf(c0);
            }
            if (a1) {
                float gi = sigf(acc1[0] + x1[0]);
                float gf = sigf(acc1[1] + x1[1]);
                float gg = tanhf(acc1[2] + x1[2]);
                float go = sigf(acc1[3] + x1[3]);
                c1 = gf * c1 + gi * gg;
                hbuf[1][u] = go * tanhf(c1);
            }
        }
        __syncthreads();       // h visible; also guards red reuse

        // partial logits: thread (kkq, seg) sums 32 hidden units
        float ps0 = 0.f, ps1 = 0.f;
        #pragma unroll
        for (int j = 0; j < 32; ++j) {
            int x = (seg << 5) + j;
            float wv = wcs[kkq][x];
            ps0 += wv * hbuf[0][x];
            ps1 += wv * hbuf[1][x];
        }
        red[0][kkq][seg] = ps0;
        red[1][kkq][seg] = ps1;
        __syncthreads();
        if (u < 64) {
            int b = u >> 5, kk = u & 31;
            float s = 0.f;
            #pragma unroll
            for (int sg = 0; sg < 8; ++sg) s += red[b][kk][sg];
            if (dir == 0) s += bclf[kk];
            out[((size_t)(b0 + b) * NT + t) * NK + kk] = s;
        }
    }
}

// ---------------- logits += bwd partial
__global__ void k_add(float* __restrict__ out, const float* __restrict__ part, int n) {
    int i = blockIdx.x * 256 + threadIdx.x;
    if (i < n) out[i] += part[i];
}

// ---------------- Viterbi: one wave per batch; hist in LDS; ref-exact rounding order
__global__ __launch_bounds__(64)
void k_viterbi(const float* __restrict__ logits, const int* __restrict__ lengths,
               const float* __restrict__ st, const float* __restrict__ et,
               const float* __restrict__ trans, float* __restrict__ preds) {
    int b = blockIdx.x, lane = threadIdx.x;
    __shared__ unsigned char hist[NT - 1][NK];
    int len = lengths[b];
    int k = lane & 31;
    float wt[32];
    #pragma unroll
    for (int j = 0; j < 32; ++j) wt[j] = trans[j * NK + k];
    const float* lg = logits + (size_t)b * NT * NK;
    float score = st[k] + lg[k];
    for (int t = 1; t < NT; ++t) {
        float emis = lg[t * NK + k];
        float best = -3.4e38f; int bidx = 0;
        #pragma unroll
        for (int j = 0; j < 32; ++j) {
            // exactly ref's association: fl(fl(score+trans)+emis), strict > keeps first max
            float cand = (__shfl(score, j, 64) + wt[j]) + emis;
            if (cand > best) { best = cand; bidx = j; }
        }
        bool m = t < len;
        if (lane < 32) hist[t - 1][k] = (unsigned char)(m ? bidx : k);
        score = m ? best : score;
    }
    score += et[k];
    float bv = -3.4e38f; int btag = 0;
    #pragma unroll
    for (int j = 0; j < 32; ++j) {
        float v = __shfl(score, j, 64);
        if (v > bv) { bv = v; btag = j; }
    }
    __syncthreads();
    if (lane == 0) {
        int tag = btag;
        for (int t = NT - 1; t >= 1; --t) {
            preds[(size_t)b * NT + t] = (t < len) ? (float)tag : 0.f;
            tag = hist[t - 1][tag];
        }
        preds[(size_t)b * NT] = (float)tag;   // t=0 always valid (len >= T/2)
    }
}

extern "C" void kernel_launch(void* const* d_in, const int* in_sizes, int n_in,
                              void* d_out, int out_size, void* d_ws, size_t ws_size,
                              hipStream_t stream) {
    (void)in_sizes; (void)n_in; (void)out_size;
    const float* x       = (const float*)d_in[0];
    const int*   lengths = (const int*)d_in[1];
    // d_in[2] = mask: ignored, recomputed from lengths
    const float* Wih_f = (const float*)d_in[3];
    const float* Whh_f = (const float*)d_in[4];
    const float* b_f   = (const float*)d_in[5];
    const float* Wih_b = (const float*)d_in[6];
    const float* Whh_b = (const float*)d_in[7];
    const float* b_b   = (const float*)d_in[8];
    const float* W_clf = (const float*)d_in[9];
    const float* b_clf = (const float*)d_in[10];
    const float* st    = (const float*)d_in[11];
    const float* et    = (const float*)d_in[12];
    const float* trans = (const float*)d_in[13];

    float* logits = (float*)d_out;                       // B*T*K fp32
    float* preds  = logits + (size_t)NBT * NK;           // B*T "float ints"

    char* ws = (char*)d_ws;
    size_t xpBytes   = (size_t)NBT * NG * sizeof(float); // 134 MB per direction
    size_t wsWBytes  = (size_t)2 * NH * NG * sizeof(float);
    size_t partBytes = (size_t)NBT * NK * sizeof(float);
    bool conc = ws_size >= 2 * xpBytes + wsWBytes + partBytes;

    float* xpF = (float*)ws;
    float* xpB = conc ? (float*)(ws + xpBytes) : xpF;
    float* wsW = (float*)(ws + (conc ? 2 : 1) * xpBytes);
    float* part = (float*)((char*)wsW + wsWBytes);

    k_wprep<<<2048, 256, 0, stream>>>(Whh_f, Whh_b, wsW);

    dim3 g1(NG / 64, NBT / 64);   // (16, 512)
    if (conc) {
        k_gemm_xp<<<g1, 256, 0, stream>>>(x, Wih_f, b_f, xpF);
        k_gemm_xp<<<g1, 256, 0, stream>>>(x, Wih_b, b_b, xpB);
        k_lstm<<<64, 256, 0, stream>>>(xpF, xpB, wsW, W_clf, b_clf, lengths,
                                       logits, part, 2);
    } else {
        k_gemm_xp<<<g1, 256, 0, stream>>>(x, Wih_f, b_f, xpF);
        k_lstm<<<32, 256, 0, stream>>>(xpF, xpF, wsW, W_clf, b_clf, lengths,
                                       logits, part, 0);
        k_gemm_xp<<<g1, 256, 0, stream>>>(x, Wih_b, b_b, xpF);
        k_lstm<<<32, 256, 0, stream>>>(xpF, xpF, wsW, W_clf, b_clf, lengths,
                                       logits, part, 1);
    }
    k_add<<<(NBT * NK) / 256, 256, 0, stream>>>(logits, part, NBT * NK);
    k_viterbi<<<NB, 64, 0, stream>>>(logits, lengths, st, et, trans, preds);
}